// Round 1
// baseline (456.579 us; speedup 1.0000x reference)
//
#include <hip/hip_runtime.h>
#include <cstddef>

#define H 128
#define W 192
#define KS 31
#define CF 64
#define NPIX (H*W)          // 24576
#define NKL (KS*KS)         // 961

// d_out layout (floats): out | pos | enorm | weights
#define OFF_POS (3*NPIX)            // 73728
#define OFF_EN  (OFF_POS + 2*NPIX)  // 122880
#define OFF_WGT (OFF_EN + NPIX)     // 147456

// workspace layout (floats)
#define NIMG NPIX
#define WS_CWT 0
#define WS_SWT 512
#define WS_CHT 1024
#define WS_SHT 1536
#define WS_U   2048
#define WS_V   (WS_U + 128*NIMG)
#define WS_Y   (WS_V + 128*NIMG)
#define WS_SN  (WS_Y + 128*NIMG)
#define WS_TN  (WS_SN + 64*NIMG)
#define WS_M   (WS_TN + 64*NIMG)
#define WS_RS  (WS_M + NPIX)

#define PI_F 3.14159265358979323846f

// ---------------- K1: filter tables (exact DFT sums, integer mod reduction) ---
__global__ __launch_bounds__(256) void k_tables(float* ws){
  int t = blockIdx.x*256 + threadIdx.x;
  if (t < 383){
    int d = t - 191;
    float c = 1.0f, s = 0.0f;
    for (int v = 1; v < 48; ++v){
      int m = (v*d) % 192; if (m < 0) m += 192;
      float a = (2.0f*PI_F/192.0f)*(float)m;
      c += 2.0f*cosf(a);
      s += 2.0f*sinf(a);
    }
    ws[WS_CWT + t] = c * (1.0f/192.0f);
    ws[WS_SWT + t] = s * (1.0f/192.0f);
  } else if (t < 383 + 255){
    int i = t - 383;
    int d = i - 127;
    float c = 0.0f, s = 0.0f;
    for (int u = 0; u < 32; ++u){
      int m = (u*d) % 128; if (m < 0) m += 128;
      float a = (2.0f*PI_F/128.0f)*(float)m;
      c += cosf(a);
      s += sinf(a);
    }
    ws[WS_CHT + i] = c * (1.0f/128.0f);
    ws[WS_SHT + i] = s * (1.0f/128.0f);
  }
}

// ---------------- K2: column pass  U = x*cwt, V = x*swt  ----------------------
// X is 16384 rows (128 images x 128 h) of 192 floats. Block = 8 rows.
__global__ __launch_bounds__(192) void k_colpass(const float* __restrict__ feats,
                                                const float* __restrict__ ws,
                                                float* __restrict__ U,
                                                float* __restrict__ V){
  __shared__ float xs[8][192];
  int w  = threadIdx.x;
  int R0 = blockIdx.x * 8;
  for (int r = 0; r < 8; ++r) xs[r][w] = feats[(size_t)(R0 + r)*192 + w];
  __syncthreads();
  const float* cwt = ws + WS_CWT;
  const float* swt = ws + WS_SWT;
  float u[8], v[8];
#pragma unroll
  for (int r = 0; r < 8; ++r){ u[r] = 0.0f; v[r] = 0.0f; }
  for (int wp = 0; wp < 192; ++wp){
    float cw = cwt[w - wp + 191];
    float sw = swt[w - wp + 191];
#pragma unroll
    for (int r = 0; r < 8; ++r){
      float x = xs[r][wp];
      u[r] = fmaf(x, cw, u[r]);
      v[r] = fmaf(x, sw, v[r]);
    }
  }
  for (int r = 0; r < 8; ++r){
    U[(size_t)(R0 + r)*192 + w] = u[r];
    V[(size_t)(R0 + r)*192 + w] = v[r];
  }
}

// ---------------- K3: row pass  y = Ch*U - Sh*V -------------------------------
// Block = (ch, h-tile of 16). 128ch * 8 tiles = 1024 blocks.
__global__ __launch_bounds__(192) void k_rowpass(const float* __restrict__ U,
                                                const float* __restrict__ V,
                                                const float* __restrict__ ws,
                                                float* __restrict__ Y){
  __shared__ float scht[255], ssht[255];
  int w = threadIdx.x;
  for (int i = w; i < 255; i += 192){
    scht[i] = ws[WS_CHT + i];
    ssht[i] = ws[WS_SHT + i];
  }
  __syncthreads();
  int ch = blockIdx.x >> 3;
  int h0 = (blockIdx.x & 7) * 16;
  const float* Uc = U + (size_t)ch*NIMG;
  const float* Vc = V + (size_t)ch*NIMG;
  float acc[16];
#pragma unroll
  for (int r = 0; r < 16; ++r) acc[r] = 0.0f;
  for (int hp = 0; hp < 128; ++hp){
    float uu = Uc[hp*192 + w];
    float vv = Vc[hp*192 + w];
#pragma unroll
    for (int r = 0; r < 16; ++r){
      int idx = h0 + r - hp + 127;
      acc[r] = fmaf(uu,  scht[idx], acc[r]);
      acc[r] = fmaf(-vv, ssht[idx], acc[r]);
    }
  }
  for (int r = 0; r < 16; ++r)
    Y[(size_t)ch*NIMG + (h0 + r)*192 + w] = acc[r];
}

// ---------------- K4: per-pixel channel normalization + transpose to (h,w,c) --
__global__ __launch_bounds__(192) void k_norm(const float* __restrict__ Y,
                                              float* __restrict__ SN,
                                              float* __restrict__ TN){
  int h = blockIdx.x, w = threadIdx.x;
  int pix = h*192 + w;
  float ss = 0.0f;
  for (int c = 0; c < 64; ++c){ float x = Y[(size_t)c*NIMG + pix]; ss = fmaf(x, x, ss); }
  float rn = 1.0f / sqrtf(ss);
  for (int c = 0; c < 64; ++c) SN[(size_t)pix*64 + c] = Y[(size_t)c*NIMG + pix] * rn;
  float ts = 0.0f;
  for (int c = 64; c < 128; ++c){ float x = Y[(size_t)c*NIMG + pix]; ts = fmaf(x, x, ts); }
  float rt = 1.0f / sqrtf(ts);
  for (int c = 64; c < 128; ++c) TN[(size_t)pix*64 + (c - 64)] = Y[(size_t)c*NIMG + pix] * rt;
}

// ---------------- K5: local correlation (scaled by temp) ----------------------
// Block = (h, k). Target row in registers, source row transposed in LDS.
__global__ __launch_bounds__(192) void k_corr(const float* __restrict__ SN,
                                              const float* __restrict__ TN,
                                              const int* __restrict__ temp,
                                              float* __restrict__ wgt){
  __shared__ float4 S[16][193];   // [c4][w'] padded: conflict-free b128 reads
  int h = blockIdx.x, k = blockIdx.y;
  int w = threadIdx.x;
  int sh = h + k - 15; sh = sh < 0 ? 0 : (sh > 127 ? 127 : sh);
  const float4* srow = (const float4*)(SN + (size_t)sh*192*64);
#pragma unroll
  for (int i = 0; i < 16; ++i){
    int g = w + 192*i;          // 0..3071 flat float4 index, coalesced
    S[g & 15][g >> 4] = srow[g];
  }
  float4 t[16];
  const float4* trow = (const float4*)(TN + (size_t)(h*192 + w)*64);
#pragma unroll
  for (int c4 = 0; c4 < 16; ++c4) t[c4] = trow[c4];
  __syncthreads();
  float scale = (float)(*temp);
  float* outp = wgt + (size_t)(h*192 + w)*NKL + k*KS;
  for (int l = 0; l < KS; ++l){
    int sx = w + l - 15; sx = sx < 0 ? 0 : (sx > 191 ? 191 : sx);
    float acc = 0.0f;
#pragma unroll
    for (int c4 = 0; c4 < 16; ++c4){
      float4 s = S[c4][sx];
      float4 tv = t[c4];
      acc = fmaf(tv.x, s.x, acc);
      acc = fmaf(tv.y, s.y, acc);
      acc = fmaf(tv.z, s.z, acc);
      acc = fmaf(tv.w, s.w, acc);
    }
    outp[l] = acc * scale;
  }
}

// ---------------- K6: per-pixel softmax max & 1/sum ---------------------------
__global__ __launch_bounds__(256) void k_maxsum(const float* __restrict__ wgt,
                                                float* __restrict__ M,
                                                float* __restrict__ RS){
  __shared__ float red[256];
  int pix = blockIdx.x, t = threadIdx.x;
  const float* p = wgt + (size_t)pix*NKL;
  float x[4];
#pragma unroll
  for (int j = 0; j < 4; ++j){
    int i = t + 256*j;
    x[j] = (i < NKL) ? p[i] : -3.4e38f;
  }
  float m = fmaxf(fmaxf(x[0], x[1]), fmaxf(x[2], x[3]));
  red[t] = m; __syncthreads();
  for (int s = 128; s > 0; s >>= 1){
    if (t < s) red[t] = fmaxf(red[t], red[t + s]);
    __syncthreads();
  }
  float mall = red[0]; __syncthreads();
  float sum = 0.0f;
#pragma unroll
  for (int j = 0; j < 4; ++j){
    int i = t + 256*j;
    if (i < NKL) sum += expf(x[j] - mall);
  }
  red[t] = sum; __syncthreads();
  for (int s = 128; s > 0; s >>= 1){
    if (t < s) red[t] += red[t + s];
    __syncthreads();
  }
  if (t == 0){ M[pix] = mall; RS[pix] = 1.0f / red[0]; }
}

// ---------------- K7: finalize: weights (in place), out, pos, enorm -----------
__global__ __launch_bounds__(256) void k_final(float* __restrict__ dout,
                                               const float* __restrict__ M,
                                               const float* __restrict__ RS,
                                               const float* __restrict__ frames){
  __shared__ float red[6][256];
  int pix = blockIdx.x, t = threadIdx.x;
  int h = pix / 192, w = pix % 192;
  float* wp_ = dout + OFF_WGT + (size_t)pix*NKL;
  float m = M[pix], rs = RS[pix];
  float o0=0, o1=0, o2=0, p0=0, p1=0, en=0;
#pragma unroll
  for (int j = 0; j < 4; ++j){
    int i = t + 256*j;
    if (i < NKL){
      int k = i / 31, l = i - k*31;
      float e = expf(wp_[i] - m) * rs;
      wp_[i] = e;
      float dy = (float)(k - 15), dx = (float)(l - 15);
      p0 = fmaf(e, dx, p0);
      p1 = fmaf(e, dy, p1);
      en = fmaf(e, sqrtf(dx*dx + dy*dy), en);
      int hh = h + k - 15; hh = hh < 0 ? 0 : (hh > 127 ? 127 : hh);
      int ww = w + l - 15; ww = ww < 0 ? 0 : (ww > 191 ? 191 : ww);
      const float* f = frames + hh*192 + ww;
      o0 = fmaf(e, f[0],        o0);
      o1 = fmaf(e, f[NPIX],     o1);
      o2 = fmaf(e, f[2*NPIX],   o2);
    }
  }
  red[0][t]=o0; red[1][t]=o1; red[2][t]=o2; red[3][t]=p0; red[4][t]=p1; red[5][t]=en;
  __syncthreads();
  for (int s = 128; s > 0; s >>= 1){
    if (t < s){
#pragma unroll
      for (int q = 0; q < 6; ++q) red[q][t] += red[q][t + s];
    }
    __syncthreads();
  }
  if (t == 0){
    dout[0*NPIX + pix] = red[0][0];
    dout[1*NPIX + pix] = red[1][0];
    dout[2*NPIX + pix] = red[2][0];
    dout[OFF_POS + pix*2 + 0] = red[3][0];
    dout[OFF_POS + pix*2 + 1] = red[4][0];
    dout[OFF_EN + pix] = red[5][0];
  }
}

extern "C" void kernel_launch(void* const* d_in, const int* in_sizes, int n_in,
                              void* d_out, int out_size, void* d_ws, size_t ws_size,
                              hipStream_t stream) {
  const float* frames = (const float*)d_in[0];   // (1,1,3,128,192)
  const float* feats  = (const float*)d_in[2];   // (1,2,64,128,192)
  const int*   temp   = (const int*)d_in[3];
  float* ws   = (float*)d_ws;
  float* dout = (float*)d_out;
  (void)in_sizes; (void)n_in; (void)out_size; (void)ws_size;

  float* U  = ws + WS_U;
  float* V  = ws + WS_V;
  float* Y  = ws + WS_Y;
  float* SN = ws + WS_SN;
  float* TN = ws + WS_TN;
  float* M  = ws + WS_M;
  float* RS = ws + WS_RS;

  hipLaunchKernelGGL(k_tables,  dim3(3),          dim3(256), 0, stream, ws);
  hipLaunchKernelGGL(k_colpass, dim3(2048),       dim3(192), 0, stream, feats, ws, U, V);
  hipLaunchKernelGGL(k_rowpass, dim3(1024),       dim3(192), 0, stream, U, V, ws, Y);
  hipLaunchKernelGGL(k_norm,    dim3(128),        dim3(192), 0, stream, Y, SN, TN);
  hipLaunchKernelGGL(k_corr,    dim3(128, 31),    dim3(192), 0, stream, SN, TN, temp, dout + OFF_WGT);
  hipLaunchKernelGGL(k_maxsum,  dim3(NPIX),       dim3(256), 0, stream, dout + OFF_WGT, M, RS);
  hipLaunchKernelGGL(k_final,   dim3(NPIX),       dim3(256), 0, stream, dout, M, RS, frames);
}

// Round 3
// 346.190 us; speedup vs baseline: 1.3189x; 1.3189x over previous
//
#include <hip/hip_runtime.h>
#include <cstddef>

#define H 128
#define W 192
#define KS 31
#define CF 64
#define NPIX (H*W)          // 24576
#define NKL (KS*KS)         // 961

// d_out layout (floats): out | pos | enorm | weights
#define OFF_POS (3*NPIX)            // 73728
#define OFF_EN  (OFF_POS + 2*NPIX)  // 122880
#define OFF_WGT (OFF_EN + NPIX)     // 147456

// workspace layout (floats)
#define NIMG NPIX
#define WS_CWT 0
#define WS_SWT 512
#define WS_CHT 1024
#define WS_SHT 1536
#define WS_U   2048
#define WS_V   (WS_U + 128*NIMG)
#define WS_Y   (WS_V + 128*NIMG)
#define WS_SN  (WS_Y + 128*NIMG)            // ushort[NPIX*64] viewed as floats
#define WS_TN  (WS_SN + 32*NIMG)            // NPIX*64 ushorts = 32*NIMG floats

#define PI_F 3.14159265358979323846f

typedef __attribute__((ext_vector_type(8))) short short8v;
typedef __attribute__((ext_vector_type(4))) float f32x4;

__device__ inline ushort bf16rtn(float f){
  uint u = __float_as_uint(f);
  u += 0x7fffu + ((u >> 16) & 1u);
  return (ushort)(u >> 16);
}

// ---------------- K1: filter tables (exact DFT sums, integer mod reduction) ---
__global__ __launch_bounds__(256) void k_tables(float* ws){
  int t = blockIdx.x*256 + threadIdx.x;
  if (t < 383){
    int d = t - 191;
    float c = 1.0f, s = 0.0f;
    for (int v = 1; v < 48; ++v){
      int m = (v*d) % 192; if (m < 0) m += 192;
      float a = (2.0f*PI_F/192.0f)*(float)m;
      c += 2.0f*cosf(a);
      s += 2.0f*sinf(a);
    }
    ws[WS_CWT + t] = c * (1.0f/192.0f);
    ws[WS_SWT + t] = s * (1.0f/192.0f);
  } else if (t < 383 + 255){
    int i = t - 383;
    int d = i - 127;
    float c = 0.0f, s = 0.0f;
    for (int u = 0; u < 32; ++u){
      int m = (u*d) % 128; if (m < 0) m += 128;
      float a = (2.0f*PI_F/128.0f)*(float)m;
      c += cosf(a);
      s += sinf(a);
    }
    ws[WS_CHT + i] = c * (1.0f/128.0f);
    ws[WS_SHT + i] = s * (1.0f/128.0f);
  }
}

// ---------------- K2: column pass  U = x*cwt, V = x*swt  ----------------------
__global__ __launch_bounds__(192) void k_colpass(const float* __restrict__ feats,
                                                const float* __restrict__ ws,
                                                float* __restrict__ U,
                                                float* __restrict__ V){
  __shared__ float xs[8][192];
  int w  = threadIdx.x;
  int R0 = blockIdx.x * 8;
  for (int r = 0; r < 8; ++r) xs[r][w] = feats[(size_t)(R0 + r)*192 + w];
  __syncthreads();
  const float* cwt = ws + WS_CWT;
  const float* swt = ws + WS_SWT;
  float u[8], v[8];
#pragma unroll
  for (int r = 0; r < 8; ++r){ u[r] = 0.0f; v[r] = 0.0f; }
  for (int wp = 0; wp < 192; ++wp){
    float cw = cwt[w - wp + 191];
    float sw = swt[w - wp + 191];
#pragma unroll
    for (int r = 0; r < 8; ++r){
      float x = xs[r][wp];
      u[r] = fmaf(x, cw, u[r]);
      v[r] = fmaf(x, sw, v[r]);
    }
  }
  for (int r = 0; r < 8; ++r){
    U[(size_t)(R0 + r)*192 + w] = u[r];
    V[(size_t)(R0 + r)*192 + w] = v[r];
  }
}

// ---------------- K3: row pass  y = Ch*U - Sh*V -------------------------------
__global__ __launch_bounds__(192) void k_rowpass(const float* __restrict__ U,
                                                const float* __restrict__ V,
                                                const float* __restrict__ ws,
                                                float* __restrict__ Y){
  __shared__ float scht[255], ssht[255];
  int w = threadIdx.x;
  for (int i = w; i < 255; i += 192){
    scht[i] = ws[WS_CHT + i];
    ssht[i] = ws[WS_SHT + i];
  }
  __syncthreads();
  int ch = blockIdx.x >> 3;
  int h0 = (blockIdx.x & 7) * 16;
  const float* Uc = U + (size_t)ch*NIMG;
  const float* Vc = V + (size_t)ch*NIMG;
  float acc[16];
#pragma unroll
  for (int r = 0; r < 16; ++r) acc[r] = 0.0f;
  for (int hp = 0; hp < 128; ++hp){
    float uu = Uc[hp*192 + w];
    float vv = Vc[hp*192 + w];
#pragma unroll
    for (int r = 0; r < 16; ++r){
      int idx = h0 + r - hp + 127;
      acc[r] = fmaf(uu,  scht[idx], acc[r]);
      acc[r] = fmaf(-vv, ssht[idx], acc[r]);
    }
  }
  for (int r = 0; r < 16; ++r)
    Y[(size_t)ch*NIMG + (h0 + r)*192 + w] = acc[r];
}

// ---------------- K4: per-pixel channel normalization -> bf16 (h,w,c) ---------
__global__ __launch_bounds__(192) void k_norm(const float* __restrict__ Y,
                                              ushort* __restrict__ SNh,
                                              ushort* __restrict__ TNh){
  int h = blockIdx.x, w = threadIdx.x;
  int which = blockIdx.y;                // 0 = src, 1 = tgt
  int pix = h*192 + w;
  const float* base = Y + (size_t)which*64*NIMG + pix;
  float x[64];
  float ss = 0.0f;
#pragma unroll
  for (int c = 0; c < 64; ++c){
    x[c] = base[(size_t)c*NIMG];
    ss = fmaf(x[c], x[c], ss);
  }
  float rn = 1.0f / sqrtf(ss);
  ushort* o = (which ? TNh : SNh) + (size_t)pix*64;
  // pack 8 bf16 -> 16B stores
#pragma unroll
  for (int q = 0; q < 8; ++q){
    ushort tmp[8];
#pragma unroll
    for (int e = 0; e < 8; ++e) tmp[e] = bf16rtn(x[q*8 + e] * rn);
    *reinterpret_cast<uint4*>(o + q*8) = *reinterpret_cast<const uint4*>(tmp);
  }
}

// ---------------- K5: banded-GEMM correlation via MFMA (bf16, no LDS) ---------
// Grid (128 h, 31 k), 256 threads = 4 waves; wave handles i0 in [3*wv, 3*wv+2].
__global__ __launch_bounds__(256) void k_corr(const ushort* __restrict__ SNh,
                                              const ushort* __restrict__ TNh,
                                              const int* __restrict__ temp,
                                              float* __restrict__ wgt){
  int h = blockIdx.x, k = blockIdx.y;
  int lane = threadIdx.x & 63;
  int wv = threadIdx.x >> 6;
  int i0base = wv * 3;
  int n = lane & 15, g = lane >> 4;
  float tempf = (float)(*temp);
  int sh = h + k - 15; sh = sh < 0 ? 0 : (sh > 127 ? 127 : sh);

  // A fragments: target row h, tiles i0base..i0base+2
  short8v a[3][2];
#pragma unroll
  for (int i = 0; i < 3; ++i){
    const ushort* p = TNh + ((size_t)(h*192 + (i0base + i)*16 + n))*64 + g*8;
#pragma unroll
    for (int ks = 0; ks < 2; ++ks)
      a[i][ks] = *reinterpret_cast<const short8v*>(p + ks*32);
  }
  // B fragments: source row sh, tiles j0 in [i0base-1, i0base+3]
  short8v b[5][2];
  int j0lo = i0base - 1;
#pragma unroll
  for (int j = 0; j < 5; ++j){
    int j0 = j0lo + j;
    if (j0 < 0 || j0 > 11) continue;
    const ushort* p = SNh + ((size_t)(sh*192 + j0*16 + n))*64 + g*8;
#pragma unroll
    for (int ks = 0; ks < 2; ++ks)
      b[j][ks] = *reinterpret_cast<const short8v*>(p + ks*32);
  }

  float* base = wgt + ((size_t)(h*192))*NKL + (size_t)k*KS;
#pragma unroll
  for (int i = 0; i < 3; ++i){
    int i0 = i0base + i;
#pragma unroll
    for (int dj = -1; dj <= 1; ++dj){
      int j0 = i0 + dj;
      if (j0 < 0 || j0 > 11) continue;
      int jj = i + dj + 1;
      f32x4 acc = {0.0f, 0.0f, 0.0f, 0.0f};
      acc = __builtin_amdgcn_mfma_f32_16x16x32_bf16(a[i][0], b[jj][0], acc, 0, 0, 0);
      acc = __builtin_amdgcn_mfma_f32_16x16x32_bf16(a[i][1], b[jj][1], acc, 0, 0, 0);
      int sx = j0*16 + n;
#pragma unroll
      for (int r = 0; r < 4; ++r){
        int m = g*4 + r;
        int w = i0*16 + m;
        int l = sx - w + 15;
        float v = acc[r] * tempf;
        if (l >= 0 && l <= 30) base[(size_t)w*NKL + l] = v;
        if (j0 == 0 && n == 0){
          for (int l2 = 0; l2 < 15 - w; ++l2) base[(size_t)w*NKL + l2] = v;
        }
        if (j0 == 11 && n == 15){
          for (int l2 = 207 - w; l2 <= 30; ++l2) base[(size_t)w*NKL + l2] = v;
        }
      }
    }
  }
}

// ---------------- K6: fused softmax + weights + out/pos/enorm -----------------
__global__ __launch_bounds__(256) void k_fused(float* __restrict__ dout,
                                               const float* __restrict__ frames){
  __shared__ float red[256];
  __shared__ float red6[6][256];
  int pix = blockIdx.x, t = threadIdx.x;
  int h = pix / 192, w = pix % 192;
  float* wp_ = dout + OFF_WGT + (size_t)pix*NKL;

  float x[4];
#pragma unroll
  for (int j = 0; j < 4; ++j){
    int i = t + 256*j;
    x[j] = (i < NKL) ? wp_[i] : -3.4e38f;
  }
  float m = fmaxf(fmaxf(x[0], x[1]), fmaxf(x[2], x[3]));
  red[t] = m; __syncthreads();
  for (int s = 128; s > 0; s >>= 1){
    if (t < s) red[t] = fmaxf(red[t], red[t + s]);
    __syncthreads();
  }
  float mall = red[0]; __syncthreads();

  float e[4];
  float sum = 0.0f;
#pragma unroll
  for (int j = 0; j < 4; ++j){
    int i = t + 256*j;
    e[j] = (i < NKL) ? expf(x[j] - mall) : 0.0f;
    sum += e[j];
  }
  red[t] = sum; __syncthreads();
  for (int s = 128; s > 0; s >>= 1){
    if (t < s) red[t] += red[t + s];
    __syncthreads();
  }
  float rs = 1.0f / red[0];

  float o0=0, o1=0, o2=0, p0=0, p1=0, en=0;
#pragma unroll
  for (int j = 0; j < 4; ++j){
    int i = t + 256*j;
    if (i < NKL){
      int k = i / 31, l = i - k*31;
      float ev = e[j] * rs;
      wp_[i] = ev;
      float dy = (float)(k - 15), dx = (float)(l - 15);
      p0 = fmaf(ev, dx, p0);
      p1 = fmaf(ev, dy, p1);
      en = fmaf(ev, sqrtf(dx*dx + dy*dy), en);
      int hh = h + k - 15; hh = hh < 0 ? 0 : (hh > 127 ? 127 : hh);
      int ww = w + l - 15; ww = ww < 0 ? 0 : (ww > 191 ? 191 : ww);
      const float* f = frames + hh*192 + ww;
      o0 = fmaf(ev, f[0],      o0);
      o1 = fmaf(ev, f[NPIX],   o1);
      o2 = fmaf(ev, f[2*NPIX], o2);
    }
  }
  red6[0][t]=o0; red6[1][t]=o1; red6[2][t]=o2; red6[3][t]=p0; red6[4][t]=p1; red6[5][t]=en;
  __syncthreads();
  for (int s = 128; s > 0; s >>= 1){
    if (t < s){
#pragma unroll
      for (int q = 0; q < 6; ++q) red6[q][t] += red6[q][t + s];
    }
    __syncthreads();
  }
  if (t == 0){
    dout[0*NPIX + pix] = red6[0][0];
    dout[1*NPIX + pix] = red6[1][0];
    dout[2*NPIX + pix] = red6[2][0];
    dout[OFF_POS + pix*2 + 0] = red6[3][0];
    dout[OFF_POS + pix*2 + 1] = red6[4][0];
    dout[OFF_EN + pix] = red6[5][0];
  }
}

extern "C" void kernel_launch(void* const* d_in, const int* in_sizes, int n_in,
                              void* d_out, int out_size, void* d_ws, size_t ws_size,
                              hipStream_t stream) {
  const float* frames = (const float*)d_in[0];   // (1,1,3,128,192)
  const float* feats  = (const float*)d_in[2];   // (1,2,64,128,192)
  const int*   temp   = (const int*)d_in[3];
  float* ws   = (float*)d_ws;
  float* dout = (float*)d_out;
  (void)in_sizes; (void)n_in; (void)out_size; (void)ws_size;

  float*  U   = ws + WS_U;
  float*  V   = ws + WS_V;
  float*  Y   = ws + WS_Y;
  ushort* SNh = (ushort*)(ws + WS_SN);
  ushort* TNh = (ushort*)(ws + WS_TN);

  hipLaunchKernelGGL(k_tables,  dim3(3),         dim3(256), 0, stream, ws);
  hipLaunchKernelGGL(k_colpass, dim3(2048),      dim3(192), 0, stream, feats, ws, U, V);
  hipLaunchKernelGGL(k_rowpass, dim3(1024),      dim3(192), 0, stream, U, V, ws, Y);
  hipLaunchKernelGGL(k_norm,    dim3(128, 2),    dim3(192), 0, stream, Y, SNh, TNh);
  hipLaunchKernelGGL(k_corr,    dim3(128, 31),   dim3(256), 0, stream, SNh, TNh, temp, dout + OFF_WGT);
  hipLaunchKernelGGL(k_fused,   dim3(NPIX),      dim3(256), 0, stream, dout, frames);
}